// Round 13
// baseline (128.164 us; speedup 1.0000x reference)
//
#include <hip/hip_runtime.h>
#include <hip/hip_bf16.h>
#include <stdint.h>

typedef unsigned short u16;
typedef unsigned int u32;
typedef float __attribute__((ext_vector_type(4))) f32x4;
typedef __bf16 __attribute__((ext_vector_type(8))) bfrag;
typedef u16 __attribute__((ext_vector_type(8))) u16x8;

#define DEV static __device__ __forceinline__

DEV u16 f2bf(float f) {
  union { float f; u32 u; } c; c.f = f;
  u32 u = c.u;
  u += 0x7fffu + ((u >> 16) & 1u);   // round-to-nearest-even
  return (u16)(u >> 16);
}

DEV u16 bf16bits(float f) {          // native HIP conversion (R6-proven)
  __hip_bfloat16 h = __float2bfloat16(f);
  return *reinterpret_cast<u16*>(&h);
}

DEV float exp2a(float x) { return __builtin_amdgcn_exp2f(x); }  // v_exp_f32

typedef const u32 __attribute__((address_space(1)))* gas_t;
typedef u32 __attribute__((address_space(3)))* las_t;

DEV void async16(const void* g, void* l) {
  __builtin_amdgcn_global_load_lds((gas_t)(uintptr_t)g, (las_t)(uintptr_t)l, 16, 0, 0);
}

// ---------------------------------------------------------------- convert
__global__ __launch_bounds__(256) void convert_all(
    const float* __restrict__ x, const float* __restrict__ y,
    const float* __restrict__ wq, const float* __restrict__ wk,
    const float* __restrict__ wv, const float* __restrict__ wp,
    u16* __restrict__ xb, u16* __restrict__ yb,
    u16* __restrict__ wqb, u16* __restrict__ wkb,
    u16* __restrict__ wvb, u16* __restrict__ wpb) {
  const int NX4 = (2 * 2048 * 1024) / 4;   // 1048576
  const int NW4 = (1024 * 1024) / 4;       // 262144 = 2^18
  const int total = 2 * NX4 + 4 * NW4;
  for (int i = blockIdx.x * blockDim.x + threadIdx.x; i < total;
       i += gridDim.x * blockDim.x) {
    const float4* s; ushort4* d; int off;
    if (i < NX4) { s = (const float4*)x; d = (ushort4*)xb; off = i; }
    else if (i < 2 * NX4) { s = (const float4*)y; d = (ushort4*)yb; off = i - NX4; }
    else {
      int k = i - 2 * NX4; int wsel = k >> 18; off = k & (NW4 - 1);
      s = (const float4*)(wsel == 0 ? wq : wsel == 1 ? wk : wsel == 2 ? wv : wp);
      d = (ushort4*)(wsel == 0 ? wqb : wsel == 1 ? wkb : wsel == 2 ? wvb : wpb);
    }
    float4 v = s[off];
    ushort4 o; o.x = f2bf(v.x); o.y = f2bf(v.y); o.z = f2bf(v.z); o.w = f2bf(v.w);
    d[off] = o;
  }
}

// ---------------------------------------------------------------- fused QKV GEMM
// (byte-identical to R11) BK=64, pre-swizzled global_load_lds staging,
// XOR-swizzled fragment reads; V-transpose scratch aliases staging arena.
__global__ __launch_bounds__(256, 3) void gemm_qkv(
    const u16* __restrict__ xb, const u16* __restrict__ yb,
    const u16* __restrict__ wqb, const u16* __restrict__ wkb,
    const u16* __restrict__ wvb,
    u16* __restrict__ Qb, u16* __restrict__ Kb2, u16* __restrict__ Vtb) {
  const int Kd = 1024, Nd = 1024;
  __shared__ __align__(16) u16 arena[18432];   // 36 KB
  u16* Als = arena;                            // [128][64]
  u16* Bls = arena + 8192;                     // [128][64]

  const int gid = blockIdx.x;
  const int seg = gid >> 8;            // 0:Q 1:K 2:V
  const int bb = gid & 255;
  const int m0 = (bb >> 3) * 128, n0 = (bb & 7) * 128;
  const u16* A  = (seg == 0) ? yb : xb;
  const u16* Bw = (seg == 0) ? wqb : (seg == 1 ? wkb : wvb);

  const int t = threadIdx.x;
  const int lane = t & 63, w = t >> 6;
  const int wr = w >> 1, wc = w & 1;
  const int r15 = lane & 15, g = lane >> 4;
  const int rdx = (r15 & 7) << 3;              // read-side XOR key (u16)

  const int srow = t >> 3;
  const int scol = ((t & 7) ^ (srow & 7)) * 8;

  f32x4 acc[4][4] = {{}};
  const u16* ga = A + (size_t)(m0 + srow) * Kd + scol;
  const u16* gb = Bw + (size_t)(n0 + srow) * Kd + scol;

  for (int k0 = 0; k0 < Kd; k0 += 64) {
#pragma unroll
    for (int c = 0; c < 4; ++c) {
      async16(ga + (size_t)c * 32 * Kd + k0, &Als[c * 2048 + t * 8]);
      async16(gb + (size_t)c * 32 * Kd + k0, &Bls[c * 2048 + t * 8]);
    }
    __syncthreads();
#pragma unroll
    for (int ks = 0; ks < 2; ++ks) {
      const int cb = (ks * 32 + g * 8) ^ rdx;
      bfrag af[4], bfr[4];
#pragma unroll
      for (int i = 0; i < 4; i++)
        af[i] = *(const bfrag*)&Als[(wr * 64 + i * 16 + r15) * 64 + cb];
#pragma unroll
      for (int j = 0; j < 4; j++)
        bfr[j] = *(const bfrag*)&Bls[(wc * 64 + j * 16 + r15) * 64 + cb];
#pragma unroll
      for (int i = 0; i < 4; i++)
#pragma unroll
        for (int j = 0; j < 4; j++)
          acc[i][j] = __builtin_amdgcn_mfma_f32_16x16x32_bf16(af[i], bfr[j], acc[i][j], 0, 0, 0);
    }
    __syncthreads();
  }

  if (seg < 2) {
    u16* C = (seg == 0) ? Qb : Kb2;
    const float scale = (seg == 0) ? 0.18033688f : 1.0f;  // 0.125*log2(e)
#pragma unroll
    for (int i = 0; i < 4; i++) {
#pragma unroll
      for (int j = 0; j < 4; j++) {
        int col = n0 + wc * 64 + j * 16 + r15;
        int row = m0 + wr * 64 + i * 16 + g * 4;
#pragma unroll
        for (int r = 0; r < 4; r++)
          C[(size_t)(row + r) * Nd + col] = f2bf(acc[i][j][r] * scale);
      }
    }
  } else {
    u16* Tw = arena + w * 4608;                // [64][72]
#pragma unroll
    for (int i = 0; i < 4; i++)
#pragma unroll
      for (int j = 0; j < 4; j++)
#pragma unroll
        for (int r = 0; r < 4; r++)
          Tw[(j * 16 + r15) * 72 + (i * 16 + g * 4 + r)] = f2bf(acc[i][j][r]);
#pragma unroll
    for (int it = 0; it < 8; ++it) {
      int slot = lane + it * 64;
      int nl = slot >> 3, sgm = slot & 7;
      int4 vrow = *(const int4*)&Tw[nl * 72 + sgm * 8];
      int col = n0 + wc * 64 + nl;       // = h*64 + hs
      int h = col >> 6, hs = col & 63;
      int rowg = m0 + wr * 64 + sgm * 8; // token index
      int b = rowg >> 11, s = rowg & 2047;
      *(int4*)&Vtb[(((size_t)b * 16 + h) * 64 + hs) * 2048 + s] = vrow;
    }
  }
}

// ---------------------------------------------------------------- proj GEMM
// (byte-identical to R11) BM=64 x BN=128, BK=64, grid (8,64).
__global__ __launch_bounds__(256, 2) void gemm_proj(
    const u16* __restrict__ A, const u16* __restrict__ Bw,
    float* __restrict__ C, const float* __restrict__ bias) {
  const int Kd = 1024, Nd = 1024;
  __shared__ __align__(16) u16 Als[64 * 64];    // 8 KB
  __shared__ __align__(16) u16 Bls[128 * 64];   // 16 KB
  const int t = threadIdx.x;
  const int lane = t & 63, w = t >> 6;
  const int wr = w >> 1, wc = w & 1;
  const int r15 = lane & 15, g = lane >> 4;
  const int m0 = blockIdx.y * 64, n0 = blockIdx.x * 128;
  const int rdx = (r15 & 7) << 3;
  const int srow = t >> 3;
  const int scol = ((t & 7) ^ (srow & 7)) * 8;

  f32x4 acc[2][4] = {{}};
  const u16* ga = A + (size_t)(m0 + srow) * Kd + scol;
  const u16* gb = Bw + (size_t)(n0 + srow) * Kd + scol;

  for (int k0 = 0; k0 < Kd; k0 += 64) {
#pragma unroll
    for (int c = 0; c < 2; ++c)
      async16(ga + (size_t)c * 32 * Kd + k0, &Als[c * 2048 + t * 8]);
#pragma unroll
    for (int c = 0; c < 4; ++c)
      async16(gb + (size_t)c * 32 * Kd + k0, &Bls[c * 2048 + t * 8]);
    __syncthreads();
#pragma unroll
    for (int ks = 0; ks < 2; ++ks) {
      const int cb = (ks * 32 + g * 8) ^ rdx;
      bfrag af[2], bfr[4];
#pragma unroll
      for (int i = 0; i < 2; i++)
        af[i] = *(const bfrag*)&Als[(wr * 32 + i * 16 + r15) * 64 + cb];
#pragma unroll
      for (int j = 0; j < 4; j++)
        bfr[j] = *(const bfrag*)&Bls[(wc * 64 + j * 16 + r15) * 64 + cb];
#pragma unroll
      for (int i = 0; i < 2; i++)
#pragma unroll
        for (int j = 0; j < 4; j++)
          acc[i][j] = __builtin_amdgcn_mfma_f32_16x16x32_bf16(af[i], bfr[j], acc[i][j], 0, 0, 0);
    }
    __syncthreads();
  }

#pragma unroll
  for (int i = 0; i < 2; i++) {
#pragma unroll
    for (int j = 0; j < 4; j++) {
      int col = n0 + wc * 64 + j * 16 + r15;
      int row = m0 + wr * 32 + i * 16 + g * 4;
      float bv = bias[col];
#pragma unroll
      for (int r = 0; r < 4; r++)
        C[(size_t)(row + r) * Nd + col] = acc[i][j][r] + bv;
    }
  }
}

// ---------------------------------------------------------------- attention
// NSPLIT=2: flash-decoding split-K, R12 structure with the UNIT BUG FIXED:
// ktile0 is a TILE index (split * 16); all staging/mask offsets use
// (ktile0 + kt) * 64. Partials (unnormalized O, row sums) are exactly
// additive under fixed-max softmax. NSPLIT=1: R11 single-pass (fallback).
template <int NSPLIT>
__global__ __launch_bounds__(256, 2) void attn_fwd(
    const u16* __restrict__ Q, const u16* __restrict__ Kb,
    const u16* __restrict__ Vt, const int* __restrict__ mask,
    u16* __restrict__ O, float* __restrict__ Op, float* __restrict__ Lp) {
  __shared__ __align__(16) u16 Kls[2][64 * 64];
  __shared__ __align__(16) u16 Vls[2][64 * 64];
  __shared__ __align__(16) u16 Pls[4][32 * 64];
  __shared__ float biasl[2][64];

  const int bid = blockIdx.x;
  const int swz = (bid & 7) * (NSPLIT * 64) + (bid >> 3);  // bijective XCD chunk
  const int qblk = swz & 15;
  const int split = (NSPLIT == 2) ? ((swz >> 4) & 1) : 0;
  const int bh = (NSPLIT == 2) ? (swz >> 5) : (swz >> 4);
  const int b = bh >> 4, h = bh & 15;
  const int t = threadIdx.x, lane = t & 63, w = t >> 6;
  const int r15 = lane & 15, g = lane >> 4;
  const int qbase = qblk * 128 + w * 32;
  const int ktile0 = split * (32 / NSPLIT);    // first KV TILE index (FIX)
  const int NT = 32 / NSPLIT;                  // tiles this block

  bfrag aQ[2][2];
  {
    const u16* Qg = Q + ((size_t)b * 2048 + qbase) * 1024 + h * 64;
#pragma unroll
    for (int mf = 0; mf < 2; ++mf)
#pragma unroll
      for (int ks = 0; ks < 2; ++ks)
        aQ[mf][ks] = *(const bfrag*)&Qg[(size_t)(mf * 16 + r15) * 1024 + ks * 32 + g * 8];
  }

  bfrag ones;
  {
    u16x8 ob = {0x3F80, 0x3F80, 0x3F80, 0x3F80, 0x3F80, 0x3F80, 0x3F80, 0x3F80};
    ones = *(bfrag*)&ob;
  }

  f32x4 oacc[2][4] = {};
  f32x4 osum[2] = {};

  const u16* Kg = Kb + (size_t)b * 2048 * 1024 + h * 64;
  const u16* Vg = Vt + (size_t)bh * 64 * 2048;
  const int* mg = mask + b * 2048;

  const int rdx = (r15 & 7) << 3;              // read-side XOR key (u16)
  const int srow = t >> 3;                     // 0..31
  const int scol = (((t & 7) ^ (srow & 7)) * 8);

  auto stage_async = [&](int kv0, int buf) {   // kv0 in KEY units
    async16(&Kg[(size_t)(kv0 + srow) * 1024 + scol],        &Kls[buf][t * 8]);
    async16(&Kg[(size_t)(kv0 + 32 + srow) * 1024 + scol],   &Kls[buf][2048 + t * 8]);
    async16(&Vg[(size_t)srow * 2048 + kv0 + scol],          &Vls[buf][t * 8]);
    async16(&Vg[(size_t)(32 + srow) * 2048 + kv0 + scol],   &Vls[buf][2048 + t * 8]);
  };

  stage_async(ktile0 * 64, 0);
  if (t < 64) biasl[0][t] = mg[ktile0 * 64 + t] ? 0.f : -1e30f;
  __syncthreads();                             // drains vmcnt: tile 0 ready

  float nbias = 0.f;
  for (int kt = 0; kt < NT; ++kt) {
    const int cur = kt & 1;
    if (kt < NT - 1) {
      int nkv = (ktile0 + kt + 1) * 64;        // KEY units (FIX)
      stage_async(nkv, cur ^ 1);               // async prefetch into idle buf
      if (t < 64) nbias = mg[nkv + t] ? 0.f : -1e30f;
    }

    // ---- QK^T
    f32x4 sc[2][4] = {};
    __builtin_amdgcn_s_setprio(1);
#pragma unroll
    for (int ks = 0; ks < 2; ++ks) {
      const int cb = (ks * 32 + g * 8) ^ rdx;
#pragma unroll
      for (int nf = 0; nf < 4; ++nf) {
        bfrag bK = *(const bfrag*)&Kls[cur][(nf * 16 + r15) * 64 + cb];
#pragma unroll
        for (int mf = 0; mf < 2; ++mf)
          sc[mf][nf] = __builtin_amdgcn_mfma_f32_16x16x32_bf16(aQ[mf][ks], bK, sc[mf][nf], 0, 0, 0);
      }
    }
    __builtin_amdgcn_s_setprio(0);

    // ---- P = exp2(score + maskbias), no max tracking
    float bcol[4];
#pragma unroll
    for (int nf = 0; nf < 4; ++nf) bcol[nf] = biasl[cur][nf * 16 + r15];

#pragma unroll
    for (int mf = 0; mf < 2; ++mf)
#pragma unroll
      for (int i = 0; i < 4; i++) {
        const int prow = mf * 16 + g * 4 + i;
        const int pxr = (prow & 7) << 3;
        u16* pr = &Pls[w][prow * 64];
#pragma unroll
        for (int nf = 0; nf < 4; ++nf) {
          float p = exp2a(sc[mf][nf][i] + bcol[nf]);
          pr[(nf * 16 + r15) ^ pxr] = bf16bits(p);
        }
      }

    // ---- PV + row-sum MFMA
    __builtin_amdgcn_s_setprio(1);
#pragma unroll
    for (int ks = 0; ks < 2; ++ks) {
      const int cb = (ks * 32 + g * 8) ^ rdx;
      bfrag aP[2];
#pragma unroll
      for (int mf = 0; mf < 2; ++mf)
        aP[mf] = *(const bfrag*)&Pls[w][(mf * 16 + r15) * 64 + cb];
#pragma unroll
      for (int nf = 0; nf < 4; ++nf) {
        bfrag bV = *(const bfrag*)&Vls[cur][(nf * 16 + r15) * 64 + cb];
#pragma unroll
        for (int mf = 0; mf < 2; ++mf)
          oacc[mf][nf] = __builtin_amdgcn_mfma_f32_16x16x32_bf16(aP[mf], bV, oacc[mf][nf], 0, 0, 0);
      }
#pragma unroll
      for (int mf = 0; mf < 2; ++mf)
        osum[mf] = __builtin_amdgcn_mfma_f32_16x16x32_bf16(aP[mf], ones, osum[mf], 0, 0, 0);
    }
    __builtin_amdgcn_s_setprio(0);

    if (kt < NT - 1 && t < 64) biasl[cur ^ 1][t] = nbias;
    __syncthreads();                           // one barrier per tile
  }

  if constexpr (NSPLIT == 1) {
    u16* Og = O + ((size_t)b * 2048 + qbase) * 1024 + h * 64;
#pragma unroll
    for (int mf = 0; mf < 2; ++mf)
#pragma unroll
      for (int i = 0; i < 4; i++) {
        float rl = 1.f / osum[mf][i];
        size_t ro = (size_t)(mf * 16 + g * 4 + i) * 1024;
#pragma unroll
        for (int nf = 0; nf < 4; ++nf)
          Og[ro + nf * 16 + r15] = f2bf(oacc[mf][nf][i] * rl);
      }
  } else {
    float* Og = Op + (size_t)split * 4194304 + ((size_t)b * 2048 + qbase) * 1024 + h * 64;
    float* Lg = Lp + (size_t)split * 65536 + ((size_t)b * 16 + h) * 2048 + qbase;
#pragma unroll
    for (int mf = 0; mf < 2; ++mf)
#pragma unroll
      for (int i = 0; i < 4; i++) {
        size_t ro = (size_t)(mf * 16 + g * 4 + i) * 1024;
#pragma unroll
        for (int nf = 0; nf < 4; ++nf)
          Og[ro + nf * 16 + r15] = oacc[mf][nf][i];   // unnormalized
        if (r15 == 0) Lg[mf * 16 + g * 4 + i] = osum[mf][i];
      }
  }
}

// ---------------------------------------------------------------- split reduce
// Ob = (Op[0] + Op[1]) / (Lp[0] + Lp[1]), bf16. 524288 x 8-elem chunks.
__global__ __launch_bounds__(256) void attn_reduce(
    const float* __restrict__ Op, const float* __restrict__ Lp,
    u16* __restrict__ Ob) {
  int idx = blockIdx.x * 256 + threadIdx.x;    // 0..524287
  int row = idx >> 7;                          // token 0..4095
  int c8 = (idx & 127) * 8;                    // d base
  int h = c8 >> 6;
  int b = row >> 11, s = row & 2047;
  int li = (b * 16 + h) * 2048 + s;
  float rl = 1.f / (Lp[li] + Lp[65536 + li]);
  const float4* p1 = (const float4*)&Op[(size_t)row * 1024 + c8];
  const float4* p2 = (const float4*)&Op[4194304 + (size_t)row * 1024 + c8];
  float4 a0 = p1[0], a1 = p1[1], b0 = p2[0], b1 = p2[1];
  ushort4 o0, o1;
  o0.x = f2bf((a0.x + b0.x) * rl); o0.y = f2bf((a0.y + b0.y) * rl);
  o0.z = f2bf((a0.z + b0.z) * rl); o0.w = f2bf((a0.w + b0.w) * rl);
  o1.x = f2bf((a1.x + b1.x) * rl); o1.y = f2bf((a1.y + b1.y) * rl);
  o1.z = f2bf((a1.z + b1.z) * rl); o1.w = f2bf((a1.w + b1.w) * rl);
  *(ushort4*)&Ob[(size_t)idx * 8] = o0;
  *(ushort4*)&Ob[(size_t)idx * 8 + 4] = o1;
}

// ---------------------------------------------------------------- launch
extern "C" void kernel_launch(void* const* d_in, const int* in_sizes, int n_in,
                              void* d_out, int out_size, void* d_ws, size_t ws_size,
                              hipStream_t stream) {
  const float* x  = (const float*)d_in[0];
  const float* y  = (const float*)d_in[1];
  const int*  msk = (const int*)d_in[2];
  const float* Wq = (const float*)d_in[3];
  const float* Wk = (const float*)d_in[4];
  const float* Wv = (const float*)d_in[5];
  const float* Wp = (const float*)d_in[6];
  const float* bp = (const float*)d_in[7];

  char* ws = (char*)d_ws;
  const size_t SZ_XB = (size_t)2 * 2048 * 1024 * 2;  // 8 MiB (bf16 [B,S,D])
  const size_t SZ_W  = (size_t)1024 * 1024 * 2;      // 2 MiB (bf16 [D,D])
  u16* xb  = (u16*)(ws);
  u16* yb  = (u16*)(ws + SZ_XB);
  u16* wqb = (u16*)(ws + 2 * SZ_XB);
  u16* wkb = (u16*)(ws + 2 * SZ_XB + SZ_W);
  u16* wvb = (u16*)(ws + 2 * SZ_XB + 2 * SZ_W);
  u16* wpb = (u16*)(ws + 2 * SZ_XB + 3 * SZ_W);
  u16* Qb  = (u16*)(ws + 2 * SZ_XB + 4 * SZ_W);
  u16* Kb2 = (u16*)(ws + 3 * SZ_XB + 4 * SZ_W);
  u16* Vtb = (u16*)(ws + 4 * SZ_XB + 4 * SZ_W);
  u16* Ob  = (u16*)(ws + 5 * SZ_XB + 4 * SZ_W);
  // split-K scratch: both 16 MiB O-partials appended at ws+56 MiB; row-sum
  // partials (512 KiB) overlay wqb (dead after gemm_qkv).
  float* Lp = (float*)(ws + 2 * SZ_XB);
  const size_t OFF_OP = 6 * SZ_XB + 4 * SZ_W;              // 56 MiB
  const size_t NEED = OFF_OP + (size_t)2 * 4194304 * 4;    // 88 MiB

  convert_all<<<2048, 256, 0, stream>>>(x, y, Wq, Wk, Wv, Wp, xb, yb, wqb, wkb, wvb, wpb);
  gemm_qkv<<<768, 256, 0, stream>>>(xb, yb, wqb, wkb, wvb, Qb, Kb2, Vtb);
  if (ws_size >= NEED) {
    float* Op = (float*)(ws + OFF_OP);
    attn_fwd<2><<<1024, 256, 0, stream>>>(Qb, Kb2, Vtb, msk, nullptr, Op, Lp);
    attn_reduce<<<2048, 256, 0, stream>>>(Op, Lp, Ob);
  } else {
    attn_fwd<1><<<512, 256, 0, stream>>>(Qb, Kb2, Vtb, msk, Ob, nullptr, nullptr);
  }
  dim3 gg(8, 64);
  gemm_proj<<<gg, 256, 0, stream>>>(Ob, wpb, (float*)d_out, bp);
}

// Round 14
// 113.843 us; speedup vs baseline: 1.1258x; 1.1258x over previous
//
#include <hip/hip_runtime.h>
#include <hip/hip_bf16.h>
#include <stdint.h>

typedef unsigned short u16;
typedef unsigned int u32;
typedef float __attribute__((ext_vector_type(4))) f32x4;
typedef __bf16 __attribute__((ext_vector_type(8))) bfrag;
typedef u16 __attribute__((ext_vector_type(8))) u16x8;

#define DEV static __device__ __forceinline__

DEV u16 f2bf(float f) {
  union { float f; u32 u; } c; c.f = f;
  u32 u = c.u;
  u += 0x7fffu + ((u >> 16) & 1u);   // round-to-nearest-even
  return (u16)(u >> 16);
}

DEV u16 bf16bits(float f) {          // native HIP conversion (R6-proven)
  __hip_bfloat16 h = __float2bfloat16(f);
  return *reinterpret_cast<u16*>(&h);
}

DEV float exp2a(float x) { return __builtin_amdgcn_exp2f(x); }  // v_exp_f32

typedef const u32 __attribute__((address_space(1)))* gas_t;
typedef u32 __attribute__((address_space(3)))* las_t;

DEV void async16(const void* g, void* l) {
  __builtin_amdgcn_global_load_lds((gas_t)(uintptr_t)g, (las_t)(uintptr_t)l, 16, 0, 0);
}

// ---------------------------------------------------------------- convert
__global__ __launch_bounds__(256) void convert_all(
    const float* __restrict__ x, const float* __restrict__ y,
    const float* __restrict__ wq, const float* __restrict__ wk,
    const float* __restrict__ wv, const float* __restrict__ wp,
    u16* __restrict__ xb, u16* __restrict__ yb,
    u16* __restrict__ wqb, u16* __restrict__ wkb,
    u16* __restrict__ wvb, u16* __restrict__ wpb) {
  const int NX4 = (2 * 2048 * 1024) / 4;   // 1048576
  const int NW4 = (1024 * 1024) / 4;       // 262144 = 2^18
  const int total = 2 * NX4 + 4 * NW4;
  for (int i = blockIdx.x * blockDim.x + threadIdx.x; i < total;
       i += gridDim.x * blockDim.x) {
    const float4* s; ushort4* d; int off;
    if (i < NX4) { s = (const float4*)x; d = (ushort4*)xb; off = i; }
    else if (i < 2 * NX4) { s = (const float4*)y; d = (ushort4*)yb; off = i - NX4; }
    else {
      int k = i - 2 * NX4; int wsel = k >> 18; off = k & (NW4 - 1);
      s = (const float4*)(wsel == 0 ? wq : wsel == 1 ? wk : wsel == 2 ? wv : wp);
      d = (ushort4*)(wsel == 0 ? wqb : wsel == 1 ? wkb : wsel == 2 ? wvb : wpb);
    }
    float4 v = s[off];
    ushort4 o; o.x = f2bf(v.x); o.y = f2bf(v.y); o.z = f2bf(v.z); o.w = f2bf(v.w);
    d[off] = o;
  }
}

// ---------------------------------------------------------------- fused QKV GEMM
// (byte-identical to R11) BK=64, pre-swizzled global_load_lds staging,
// XOR-swizzled fragment reads; V-transpose scratch aliases staging arena.
__global__ __launch_bounds__(256, 3) void gemm_qkv(
    const u16* __restrict__ xb, const u16* __restrict__ yb,
    const u16* __restrict__ wqb, const u16* __restrict__ wkb,
    const u16* __restrict__ wvb,
    u16* __restrict__ Qb, u16* __restrict__ Kb2, u16* __restrict__ Vtb) {
  const int Kd = 1024, Nd = 1024;
  __shared__ __align__(16) u16 arena[18432];   // 36 KB
  u16* Als = arena;                            // [128][64]
  u16* Bls = arena + 8192;                     // [128][64]

  const int gid = blockIdx.x;
  const int seg = gid >> 8;            // 0:Q 1:K 2:V
  const int bb = gid & 255;
  const int m0 = (bb >> 3) * 128, n0 = (bb & 7) * 128;
  const u16* A  = (seg == 0) ? yb : xb;
  const u16* Bw = (seg == 0) ? wqb : (seg == 1 ? wkb : wvb);

  const int t = threadIdx.x;
  const int lane = t & 63, w = t >> 6;
  const int wr = w >> 1, wc = w & 1;
  const int r15 = lane & 15, g = lane >> 4;
  const int rdx = (r15 & 7) << 3;              // read-side XOR key (u16)

  const int srow = t >> 3;
  const int scol = ((t & 7) ^ (srow & 7)) * 8;

  f32x4 acc[4][4] = {{}};
  const u16* ga = A + (size_t)(m0 + srow) * Kd + scol;
  const u16* gb = Bw + (size_t)(n0 + srow) * Kd + scol;

  for (int k0 = 0; k0 < Kd; k0 += 64) {
#pragma unroll
    for (int c = 0; c < 4; ++c) {
      async16(ga + (size_t)c * 32 * Kd + k0, &Als[c * 2048 + t * 8]);
      async16(gb + (size_t)c * 32 * Kd + k0, &Bls[c * 2048 + t * 8]);
    }
    __syncthreads();
#pragma unroll
    for (int ks = 0; ks < 2; ++ks) {
      const int cb = (ks * 32 + g * 8) ^ rdx;
      bfrag af[4], bfr[4];
#pragma unroll
      for (int i = 0; i < 4; i++)
        af[i] = *(const bfrag*)&Als[(wr * 64 + i * 16 + r15) * 64 + cb];
#pragma unroll
      for (int j = 0; j < 4; j++)
        bfr[j] = *(const bfrag*)&Bls[(wc * 64 + j * 16 + r15) * 64 + cb];
#pragma unroll
      for (int i = 0; i < 4; i++)
#pragma unroll
        for (int j = 0; j < 4; j++)
          acc[i][j] = __builtin_amdgcn_mfma_f32_16x16x32_bf16(af[i], bfr[j], acc[i][j], 0, 0, 0);
    }
    __syncthreads();
  }

  if (seg < 2) {
    u16* C = (seg == 0) ? Qb : Kb2;
    const float scale = (seg == 0) ? 0.18033688f : 1.0f;  // 0.125*log2(e)
#pragma unroll
    for (int i = 0; i < 4; i++) {
#pragma unroll
      for (int j = 0; j < 4; j++) {
        int col = n0 + wc * 64 + j * 16 + r15;
        int row = m0 + wr * 64 + i * 16 + g * 4;
#pragma unroll
        for (int r = 0; r < 4; r++)
          C[(size_t)(row + r) * Nd + col] = f2bf(acc[i][j][r] * scale);
      }
    }
  } else {
    u16* Tw = arena + w * 4608;                // [64][72]
#pragma unroll
    for (int i = 0; i < 4; i++)
#pragma unroll
      for (int j = 0; j < 4; j++)
#pragma unroll
        for (int r = 0; r < 4; r++)
          Tw[(j * 16 + r15) * 72 + (i * 16 + g * 4 + r)] = f2bf(acc[i][j][r]);
#pragma unroll
    for (int it = 0; it < 8; ++it) {
      int slot = lane + it * 64;
      int nl = slot >> 3, sgm = slot & 7;
      int4 vrow = *(const int4*)&Tw[nl * 72 + sgm * 8];
      int col = n0 + wc * 64 + nl;       // = h*64 + hs
      int h = col >> 6, hs = col & 63;
      int rowg = m0 + wr * 64 + sgm * 8; // token index
      int b = rowg >> 11, s = rowg & 2047;
      *(int4*)&Vtb[(((size_t)b * 16 + h) * 64 + hs) * 2048 + s] = vrow;
    }
  }
}

// ---------------------------------------------------------------- proj GEMM
// (byte-identical to R11) BM=64 x BN=128, BK=64, grid (8,64).
__global__ __launch_bounds__(256, 2) void gemm_proj(
    const u16* __restrict__ A, const u16* __restrict__ Bw,
    float* __restrict__ C, const float* __restrict__ bias) {
  const int Kd = 1024, Nd = 1024;
  __shared__ __align__(16) u16 Als[64 * 64];    // 8 KB
  __shared__ __align__(16) u16 Bls[128 * 64];   // 16 KB
  const int t = threadIdx.x;
  const int lane = t & 63, w = t >> 6;
  const int wr = w >> 1, wc = w & 1;
  const int r15 = lane & 15, g = lane >> 4;
  const int m0 = blockIdx.y * 64, n0 = blockIdx.x * 128;
  const int rdx = (r15 & 7) << 3;
  const int srow = t >> 3;
  const int scol = ((t & 7) ^ (srow & 7)) * 8;

  f32x4 acc[2][4] = {{}};
  const u16* ga = A + (size_t)(m0 + srow) * Kd + scol;
  const u16* gb = Bw + (size_t)(n0 + srow) * Kd + scol;

  for (int k0 = 0; k0 < Kd; k0 += 64) {
#pragma unroll
    for (int c = 0; c < 2; ++c)
      async16(ga + (size_t)c * 32 * Kd + k0, &Als[c * 2048 + t * 8]);
#pragma unroll
    for (int c = 0; c < 4; ++c)
      async16(gb + (size_t)c * 32 * Kd + k0, &Bls[c * 2048 + t * 8]);
    __syncthreads();
#pragma unroll
    for (int ks = 0; ks < 2; ++ks) {
      const int cb = (ks * 32 + g * 8) ^ rdx;
      bfrag af[2], bfr[4];
#pragma unroll
      for (int i = 0; i < 2; i++)
        af[i] = *(const bfrag*)&Als[(wr * 32 + i * 16 + r15) * 64 + cb];
#pragma unroll
      for (int j = 0; j < 4; j++)
        bfr[j] = *(const bfrag*)&Bls[(wc * 64 + j * 16 + r15) * 64 + cb];
#pragma unroll
      for (int i = 0; i < 2; i++)
#pragma unroll
        for (int j = 0; j < 4; j++)
          acc[i][j] = __builtin_amdgcn_mfma_f32_16x16x32_bf16(af[i], bfr[j], acc[i][j], 0, 0, 0);
    }
    __syncthreads();
  }

#pragma unroll
  for (int i = 0; i < 2; i++) {
#pragma unroll
    for (int j = 0; j < 4; j++) {
      int col = n0 + wc * 64 + j * 16 + r15;
      int row = m0 + wr * 32 + i * 16 + g * 4;
      float bv = bias[col];
#pragma unroll
      for (int r = 0; r < 4; r++)
        C[(size_t)(row + r) * Nd + col] = acc[i][j][r] + bv;
    }
  }
}

// ---------------------------------------------------------------- attention
// R11 structure restored (single-pass, 512 blocks x 4 waves, 32 q-rows/wave,
// dbuf K/V via pre-swizzled global_load_lds, ONE barrier/tile, fixed-max
// exp2 softmax, ones-MFMA row sums, T5 setprio). Change vs R11: mask bias
// hoisted to one LDS table (8 KB) filled once — deletes per-tile mask
// global loads and the double-buffered bias writes.
__global__ __launch_bounds__(256, 2) void attn_fwd(
    const u16* __restrict__ Q, const u16* __restrict__ Kb,
    const u16* __restrict__ Vt, const int* __restrict__ mask,
    u16* __restrict__ O) {
  __shared__ __align__(16) u16 Kls[2][64 * 64];
  __shared__ __align__(16) u16 Vls[2][64 * 64];
  __shared__ __align__(16) u16 Pls[4][32 * 64];
  __shared__ float biasl[2048];

  const int bid = blockIdx.x;
  const int swz = (bid & 7) * 64 + (bid >> 3);    // bijective, XCD-chunked (512=8*64)
  const int qblk = swz & 15, bh = swz >> 4;
  const int b = bh >> 4, h = bh & 15;
  const int t = threadIdx.x, lane = t & 63, w = t >> 6;
  const int r15 = lane & 15, g = lane >> 4;
  const int qbase = qblk * 128 + w * 32;

  bfrag aQ[2][2];
  {
    const u16* Qg = Q + ((size_t)b * 2048 + qbase) * 1024 + h * 64;
#pragma unroll
    for (int mf = 0; mf < 2; ++mf)
#pragma unroll
      for (int ks = 0; ks < 2; ++ks)
        aQ[mf][ks] = *(const bfrag*)&Qg[(size_t)(mf * 16 + r15) * 1024 + ks * 32 + g * 8];
  }

  bfrag ones;
  {
    u16x8 ob = {0x3F80, 0x3F80, 0x3F80, 0x3F80, 0x3F80, 0x3F80, 0x3F80, 0x3F80};
    ones = *(bfrag*)&ob;
  }

  f32x4 oacc[2][4] = {};
  f32x4 osum[2] = {};

  const u16* Kg = Kb + (size_t)b * 2048 * 1024 + h * 64;
  const u16* Vg = Vt + (size_t)bh * 64 * 2048;
  const int* mg = mask + b * 2048;

  const int rdx = (r15 & 7) << 3;              // read-side XOR key (u16)
  const int srow = t >> 3;                     // 0..31
  const int scol = (((t & 7) ^ (srow & 7)) * 8);

  auto stage_async = [&](int kv0, int buf) {
    async16(&Kg[(size_t)(kv0 + srow) * 1024 + scol],        &Kls[buf][t * 8]);
    async16(&Kg[(size_t)(kv0 + 32 + srow) * 1024 + scol],   &Kls[buf][2048 + t * 8]);
    async16(&Vg[(size_t)srow * 2048 + kv0 + scol],          &Vls[buf][t * 8]);
    async16(&Vg[(size_t)(32 + srow) * 2048 + kv0 + scol],   &Vls[buf][2048 + t * 8]);
  };

  stage_async(0, 0);
#pragma unroll
  for (int i = 0; i < 8; ++i)                  // whole mask -> bias table once
    biasl[t + i * 256] = mg[t + i * 256] ? 0.f : -1e30f;
  __syncthreads();                             // drains vmcnt: tile 0 ready

  for (int kt = 0; kt < 32; ++kt) {
    const int cur = kt & 1;
    const int kv0 = kt * 64;
    if (kt < 31) stage_async(kv0 + 64, cur ^ 1);   // async prefetch, idle buf

    // ---- QK^T
    f32x4 sc[2][4] = {};
    __builtin_amdgcn_s_setprio(1);
#pragma unroll
    for (int ks = 0; ks < 2; ++ks) {
      const int cb = (ks * 32 + g * 8) ^ rdx;
#pragma unroll
      for (int nf = 0; nf < 4; ++nf) {
        bfrag bK = *(const bfrag*)&Kls[cur][(nf * 16 + r15) * 64 + cb];
#pragma unroll
        for (int mf = 0; mf < 2; ++mf)
          sc[mf][nf] = __builtin_amdgcn_mfma_f32_16x16x32_bf16(aQ[mf][ks], bK, sc[mf][nf], 0, 0, 0);
      }
    }
    __builtin_amdgcn_s_setprio(0);

    // ---- P = exp2(score + maskbias), no max tracking
    float bcol[4];
#pragma unroll
    for (int nf = 0; nf < 4; ++nf) bcol[nf] = biasl[kv0 + nf * 16 + r15];

#pragma unroll
    for (int mf = 0; mf < 2; ++mf)
#pragma unroll
      for (int i = 0; i < 4; i++) {
        const int prow = mf * 16 + g * 4 + i;
        const int pxr = (prow & 7) << 3;
        u16* pr = &Pls[w][prow * 64];
#pragma unroll
        for (int nf = 0; nf < 4; ++nf) {
          float p = exp2a(sc[mf][nf][i] + bcol[nf]);
          pr[(nf * 16 + r15) ^ pxr] = bf16bits(p);
        }
      }

    // ---- PV + row-sum MFMA
    __builtin_amdgcn_s_setprio(1);
#pragma unroll
    for (int ks = 0; ks < 2; ++ks) {
      const int cb = (ks * 32 + g * 8) ^ rdx;
      bfrag aP[2];
#pragma unroll
      for (int mf = 0; mf < 2; ++mf)
        aP[mf] = *(const bfrag*)&Pls[w][(mf * 16 + r15) * 64 + cb];
#pragma unroll
      for (int nf = 0; nf < 4; ++nf) {
        bfrag bV = *(const bfrag*)&Vls[cur][(nf * 16 + r15) * 64 + cb];
#pragma unroll
        for (int mf = 0; mf < 2; ++mf)
          oacc[mf][nf] = __builtin_amdgcn_mfma_f32_16x16x32_bf16(aP[mf], bV, oacc[mf][nf], 0, 0, 0);
      }
#pragma unroll
      for (int mf = 0; mf < 2; ++mf)
        osum[mf] = __builtin_amdgcn_mfma_f32_16x16x32_bf16(aP[mf], ones, osum[mf], 0, 0, 0);
    }
    __builtin_amdgcn_s_setprio(0);

    __syncthreads();                           // one barrier: drains prefetch,
  }                                            // publishes next tile

  u16* Og = O + ((size_t)b * 2048 + qbase) * 1024 + h * 64;
#pragma unroll
  for (int mf = 0; mf < 2; ++mf)
#pragma unroll
    for (int i = 0; i < 4; i++) {
      float rl = 1.f / osum[mf][i];             // row sum from ones-MFMA
      size_t ro = (size_t)(mf * 16 + g * 4 + i) * 1024;
#pragma unroll
      for (int nf = 0; nf < 4; ++nf)
        Og[ro + nf * 16 + r15] = f2bf(oacc[mf][nf][i] * rl);
    }
}

// ---------------------------------------------------------------- launch
extern "C" void kernel_launch(void* const* d_in, const int* in_sizes, int n_in,
                              void* d_out, int out_size, void* d_ws, size_t ws_size,
                              hipStream_t stream) {
  const float* x  = (const float*)d_in[0];
  const float* y  = (const float*)d_in[1];
  const int*  msk = (const int*)d_in[2];
  const float* Wq = (const float*)d_in[3];
  const float* Wk = (const float*)d_in[4];
  const float* Wv = (const float*)d_in[5];
  const float* Wp = (const float*)d_in[6];
  const float* bp = (const float*)d_in[7];

  char* ws = (char*)d_ws;
  const size_t SZ_XB = (size_t)2 * 2048 * 1024 * 2;  // 8 MiB (bf16 [B,S,D])
  const size_t SZ_W  = (size_t)1024 * 1024 * 2;      // 2 MiB (bf16 [D,D])
  u16* xb  = (u16*)(ws);
  u16* yb  = (u16*)(ws + SZ_XB);
  u16* wqb = (u16*)(ws + 2 * SZ_XB);
  u16* wkb = (u16*)(ws + 2 * SZ_XB + SZ_W);
  u16* wvb = (u16*)(ws + 2 * SZ_XB + 2 * SZ_W);
  u16* wpb = (u16*)(ws + 2 * SZ_XB + 3 * SZ_W);
  u16* Qb  = (u16*)(ws + 2 * SZ_XB + 4 * SZ_W);
  u16* Kb2 = (u16*)(ws + 3 * SZ_XB + 4 * SZ_W);
  u16* Vtb = (u16*)(ws + 4 * SZ_XB + 4 * SZ_W);
  u16* Ob  = (u16*)(ws + 5 * SZ_XB + 4 * SZ_W);

  convert_all<<<2048, 256, 0, stream>>>(x, y, Wq, Wk, Wv, Wp, xb, yb, wqb, wkb, wvb, wpb);
  gemm_qkv<<<768, 256, 0, stream>>>(xb, yb, wqb, wkb, wvb, Qb, Kb2, Vtb);
  attn_fwd<<<512, 256, 0, stream>>>(Qb, Kb2, Vtb, msk, Ob);
  dim3 gg(8, 64);
  gemm_proj<<<gg, 256, 0, stream>>>(Ob, wpb, (float*)d_out, bp);
}